// Round 20
// baseline (342.363 us; speedup 1.0000x reference)
//
#include <hip/hip_runtime.h>
#include <math.h>

// Mamba selective scan:
//   u, delta, z : (2, 2048, 1024) f32 ; A : (2048, 16) f32
//   B, C : (2, 16, 1024) f32 ; D, delta_bias : (2048,) f32 ; softplus flag
// Output y : (2, 2048, 1024) f32
//
// v25 = v24 (bf16-packed du_s, LDS 33.8 KB) + __launch_bounds__(512, 8):
//   r19 post-mortem: v24's LDS cut worked but the allocator RELAXED to a
//   4-wave/SIMD budget (VGPR 64 -> 128) -> 2 blocks/CU, 19% occupancy,
//   55.6 us. v23 (identical register-resident state) compiled at exactly
//   64 VGPR -> the structure FITS a 64-reg allocation; pin it with the
//   occupancy hint. 8 waves/EU * 4 EU = 32 waves/CU = 4 blocks/CU with
//   LDS 33.8 KB <= 40 KB -> even grid tiling (1024 = 4 x 256), no tail.
//   NOT the r2/r4 failure mode (no deep architectural liveness here).
//   Tripwires: VGPR == 64, WRITE_SIZE == 16384 KB (scratch check),
//   absmax <= 0.5. Fallback if spill: v23 (43.2 us).
constexpr int Bsz = 2, Dm = 2048, L = 1024, N = 16;
constexpr int CL = 16;          // chunk length (steps per lane)
constexpr int WPR = 2;          // waves per row
constexpr int RPB = 4;          // rows per block
constexpr int TPB = RPB * WPR * 64;  // 512
constexpr int NT = 8;           // pass-1 tiles (2 steps each)
constexpr int ISTR2 = 65;       // du_s u32 stride per step (64 + 1 pad)
constexpr int LROW2 = CL * ISTR2;    // 1040 u32 per row
constexpr int TS2 = 8 * 65;     // 520 float2: one step-group (8 j-rows x 65)
constexpr float LOG2E = 1.4426950408889634f;
constexpr float RLOG2E = 0.6931471805599453f;   // ln 2

#define EXP2(x) __builtin_amdgcn_exp2f(x)

typedef __attribute__((ext_vector_type(2))) float f32x2;

__device__ __forceinline__ f32x2 pk_fma(f32x2 a, f32x2 b, f32x2 c) {
    return __builtin_elementwise_fma(a, b, c);
}

// bf16 round-to-nearest-even (returns the high 16 bits)
__device__ __forceinline__ unsigned bf16_rn(float f) {
    const unsigned u = __builtin_bit_cast(unsigned, f);
    return (u + 0x7FFFu + ((u >> 16) & 1u)) >> 16;
}

// DPP lane-shift on the VALU pipe; masked/invalid lanes receive old = 0
// (identity for the affine scan). ctrl: 0x111=row_shr:1 0x112=row_shr:2
// 0x114=row_shr:4 0x118=row_shr:8 0x142=row_bcast:15.
#define DPPF(CTRL, RM, v) __builtin_bit_cast(float, __builtin_amdgcn_update_dpp( \
        0, __builtin_bit_cast(int, (float)(v)), (CTRL), (RM), 0xF, false))

// One affine-scan stage over (ss, x[8]) with window-decay exp2(A2[n]*ss).
// r9-verified machinery (absmax-clean), incl. the 0xA mask on row_bcast.
#define COMBINE_STAGE(CTRL, RM) do {                                      \
    const float ssp_ = DPPF(CTRL, RM, ss);                                \
    float xp_[8];                                                         \
    _Pragma("unroll") for (int n_ = 0; n_ < 8; ++n_)                      \
        xp_[n_] = DPPF(CTRL, RM, x[n_]);                                  \
    _Pragma("unroll") for (int n_ = 0; n_ < 8; ++n_)                      \
        x[n_] = fmaf(EXP2(A2[n_] * ss), xp_[n_], x[n_]);                  \
    ss += ssp_;                                                           \
} while (0)

// Workgroup barrier WITHOUT the vmcnt(0) drain __syncthreads inserts.
// lgkmcnt(0) makes this wave's LDS writes visible before the barrier;
// in-flight global->register loads keep counting across it.
__device__ __forceinline__ void wg_barrier() {
    asm volatile("s_waitcnt lgkmcnt(0)" ::: "memory");
    __builtin_amdgcn_s_barrier();
    asm volatile("" ::: "memory");
}

// ---------------------------------------------------------------------------
// Transform B,C into scan layout (chunk length 16), k-MAJOR:
//   Bs[b*4096 + i*256 + k*64 + cg] = float4 { B[b][4k+q][cg*16+i] } q=0..3
// Staging reads are then fully coalesced per tile.
// ---------------------------------------------------------------------------
__global__ __launch_bounds__(256) void transform_bc_kernel(
    const float* __restrict__ B_g, const float* __restrict__ C_g,
    float4* __restrict__ Bs, float4* __restrict__ Cs)
{
    const int o = threadIdx.x + 256 * blockIdx.x;   // 4096 float4 per (b, src)
    const int b = blockIdx.y;
    const float* __restrict__ src = blockIdx.z ? C_g : B_g;
    float4* __restrict__ dst = blockIdx.z ? Cs : Bs;
    const int cg = o & 63, k = (o >> 6) & 3, i = o >> 8;
    const int l = cg * CL + i;
    float4 v;
    v.x = src[(size_t)(b * N + 4 * k + 0) * L + l];
    v.y = src[(size_t)(b * N + 4 * k + 1) * L + l];
    v.z = src[(size_t)(b * N + 4 * k + 2) * L + l];
    v.w = src[(size_t)(b * N + 4 * k + 3) * L + l];
    dst[(size_t)b * 4096 + o] = v;
}

// ---------------------------------------------------------------------------
// Scan kernel. 8 waves/block = 4 rows x 2 waves. Wave handles 32 chunks of
// 16 steps. lane = h*32 + c: h = n-half, c = chunk-in-wave. cg = W*32+c.
// B/C tiles shared by all 4 rows via LDS (b64 conflict-free layout).
// ---------------------------------------------------------------------------
template<bool XF>
__global__ __launch_bounds__(TPB, 8) void mamba_scan25_kernel(
    const float* __restrict__ u_g, const float* __restrict__ delta_g,
    const float* __restrict__ A_g,
    const float* __restrict__ B_g, const float* __restrict__ C_g,
    const float4* __restrict__ Bs, const float4* __restrict__ Cs,
    const float* __restrict__ D_g, const float* __restrict__ z_g,
    const float* __restrict__ bias_g, const int* __restrict__ sp_g,
    float* __restrict__ y_g)
{
    __shared__ unsigned du_s[RPB * LROW2];  // [r][i*65+cg] = bf16(dtp)<<16|bf16(u)
    __shared__ float2 tb2[2][2 * TS2];      // 16.6 KB tile ping-pong buffers
    __shared__ float xw_s[RPB][16];         // per-row wave0 totals

    const int tid = threadIdx.x;
    const int wid = tid >> 6;                  // wave id 0..7
    const int lane = tid & 63;
    const int W = wid & 1;                     // wave-in-row
    const int r = wid >> 1;                    // local row 0..3
    const int h = lane >> 5;                   // n-half
    const int c = lane & 31;                   // chunk-in-wave
    const int cg = W * 32 + c;                 // global chunk 0..63
    const int row = blockIdx.x * RPB + r;
    const int b = row >> 11;                   // row / Dm (blocks never straddle)
    const int d = row & (Dm - 1);
    const size_t Bb = (size_t)b * 4096;        // workspace base (float4 units)
    const int lb = r * LROW2;
    const int t128 = tid & 127;                // thread-in-row (2 waves)
    // pass-1 staging: wave wid owns (il = wid>>2, k = wid&3) for all 64 cg
    const int stg0 = (wid >> 2) * TS2 + (2 * (wid & 3)) * 65 + lane;
    const int stg1 = stg0 + 65;
    // pass-2 staging: threads 0-255 stage B, 256-511 stage C (1 step each)
    const int bc = tid >> 8;
    const int t256 = tid & 255;
    const int pstg0 = bc * TS2 + (2 * ((t256 >> 6) & 3)) * 65 + (t256 & 63);
    const int pstg1 = pstg0 + 65;
    const float4* __restrict__ psrc = (bc ? Cs : Bs) + Bb;
    // tile read base for this lane: j = 4h at column cg
    const int trb = (4 * h) * 65 + cg;

    float4 s0, s1;
    if (XF) s0 = Bs[Bb + tid];                 // pass-1 tile 0, issued early

    // ---- Phase 0: coalesced load of delta/u -> step-major packed LDS ----
    {
        const float bias = bias_g[d];
        const int sp = sp_g[0];
#pragma unroll
        for (int p = 0; p < 2; ++p) {
            const int l0 = 4 * t128 + 512 * p;
            const size_t gb = (size_t)row * L + l0;
            const float4 d4 = *reinterpret_cast<const float4*>(&delta_g[gb]);
            const float4 u4 = *reinterpret_cast<const float4*>(&u_g[gb]);
#pragma unroll
            for (int k = 0; k < 4; ++k) {
                const int li = l0 + k;
                const float t = (&d4.x)[k] + bias;
                // softplus: max(t,0) + ln(1 + 2^(-|t|*log2e))
                const float e = EXP2(-fabsf(t) * LOG2E);
                const float p_ = sp ? (fmaxf(t, 0.f) +
                                       __builtin_amdgcn_logf(1.f + e) * RLOG2E)
                                    : t;
                const int a = (li & (CL - 1)) * ISTR2 + (li >> 4);
                du_s[lb + a] = (bf16_rn(p_) << 16) | bf16_rn((&u4.x)[k]);
            }
        }
    }
    float A2[8];
    f32x2 A2p[4];
#pragma unroll
    for (int g = 0; g < 2; ++g) {
        const float4 a4 = *reinterpret_cast<const float4*>(&A_g[d * N + h * 8 + g * 4]);
        A2[g * 4 + 0] = a4.x * LOG2E; A2[g * 4 + 1] = a4.y * LOG2E;
        A2[g * 4 + 2] = a4.z * LOG2E; A2[g * 4 + 3] = a4.w * LOG2E;
    }
#pragma unroll
    for (int q = 0; q < 4; ++q) { A2p[q].x = A2[2 * q]; A2p[q].y = A2[2 * q + 1]; }
    if (XF) {
        tb2[0][stg0] = make_float2(s0.x, s0.y);     // stage tile 0
        tb2[0][stg1] = make_float2(s0.z, s0.w);
        s0 = Bs[Bb + 512 + tid];                    // tile 1 (in flight)
        s1 = Bs[Bb + 1024 + tid];                   // tile 2 (in flight)
    }
    wg_barrier();

    // ---- Pass 1: zero-init scan; 8 epochs, depth-2 prefetch, pk math ----
    f32x2 x2[4];
#pragma unroll
    for (int q = 0; q < 4; ++q) { x2[q].x = 0.f; x2[q].y = 0.f; }
    float y[8];
#pragma unroll
    for (int n = 0; n < 8; ++n) y[n] = 0.f;
    float ss = 0.f;

    if (XF) {
#pragma unroll
        for (int t = 0; t < NT; ++t) {
#pragma unroll
            for (int il = 0; il < 2; ++il) {
                const int i = 2 * t + il;
                const unsigned duw = du_s[lb + i * ISTR2 + cg];
                const float dtp = __builtin_bit_cast(float, duw & 0xFFFF0000u);
                const float uu = __builtin_bit_cast(float, duw << 16);
                const float dtu = dtp * uu;
                ss += dtp;
                const int rb = il * TS2 + trb;
                f32x2 qv[4];
                qv[0] = *reinterpret_cast<const f32x2*>(&tb2[t & 1][rb]);
                qv[1] = *reinterpret_cast<const f32x2*>(&tb2[t & 1][rb + 65]);
                qv[2] = *reinterpret_cast<const f32x2*>(&tb2[t & 1][rb + 130]);
                qv[3] = *reinterpret_cast<const f32x2*>(&tb2[t & 1][rb + 195]);
                f32x2 dd; dd.x = dtp; dd.y = dtp;
                f32x2 uu2; uu2.x = dtu; uu2.y = dtu;
#pragma unroll
                for (int q = 0; q < 4; ++q) {
                    const f32x2 tq = dd * A2p[q];
                    f32x2 e; e.x = EXP2(tq.x); e.y = EXP2(tq.y);
                    const f32x2 db = uu2 * qv[q];
                    x2[q] = pk_fma(e, x2[q], db);
                }
            }
            if (t + 1 < NT) {                       // write tile t+1
                const float4 sv = (t & 1) ? s1 : s0;
                tb2[(t + 1) & 1][stg0] = make_float2(sv.x, sv.y);
                tb2[(t + 1) & 1][stg1] = make_float2(sv.z, sv.w);
            }
            if (t + 3 < NT) {                       // issue tile t+3
                if (t & 1) s1 = Bs[Bb + (t + 3) * 512 + tid];
                else       s0 = Bs[Bb + (t + 3) * 512 + tid];
            }
            if (t + 1 < NT) wg_barrier();
        }
    } else {
#pragma unroll
        for (int i = 0; i < CL; ++i) {
            const unsigned duw = du_s[lb + i * ISTR2 + cg];
            const float dtp = __builtin_bit_cast(float, duw & 0xFFFF0000u);
            const float uu = __builtin_bit_cast(float, duw << 16);
            const float dtu = dtp * uu;
            ss += dtp;
            const int l = cg * CL + i;
            const int k0 = 2 * h;
            float4 B0, B1;
#pragma unroll
            for (int q = 0; q < 4; ++q) {
                (&B0.x)[q] = B_g[(size_t)(b * N + 4 * k0 + q) * L + l];
                (&B1.x)[q] = B_g[(size_t)(b * N + 4 * k0 + 4 + q) * L + l];
            }
            const float bv[8] = {B0.x, B0.y, B0.z, B0.w, B1.x, B1.y, B1.z, B1.w};
#pragma unroll
            for (int n = 0; n < 8; ++n) {
                const float a = EXP2(dtp * A2[n]);
                const float xs = (n & 1) ? x2[n >> 1].y : x2[n >> 1].x;
                const float xn = fmaf(a, xs, dtu * bv[n]);
                if (n & 1) x2[n >> 1].y = xn; else x2[n >> 1].x = xn;
            }
        }
    }

    // unpack to scalars for the combine
    float x[8];
#pragma unroll
    for (int q = 0; q < 4; ++q) { x[2 * q] = x2[q].x; x[2 * q + 1] = x2[q].y; }

    // issue pass-2 step 0 load (latency hides under the combine)
    float4 p0, p1;
    if (XF) p0 = psrc[t256];

    // ---- Combine level 1: 32-lane segmented affine scan via DPP ----
    // After: x[n] = inclusive chunk-combine over [seg_start..c];
    //        ss   = inclusive dtp-prefix over the same window.
    COMBINE_STAGE(0x111, 0xF);   // row_shr:1
    COMBINE_STAGE(0x112, 0xF);   // row_shr:2
    COMBINE_STAGE(0x114, 0xF);   // row_shr:4
    COMBINE_STAGE(0x118, 0xF);   // row_shr:8
    COMBINE_STAGE(0x142, 0xA);   // row_bcast:15 -> rows 1,3 ONLY (r8 bug fix)

    // ---- Combine level 2 publish + stage pass-2 step 0; ONE barrier ----
    if (W == 0 && c == 31) {
#pragma unroll
        for (int n = 0; n < 8; ++n) xw_s[r][h * 8 + n] = x[n];
    }
    if (XF) {
        tb2[0][pstg0] = make_float2(p0.x, p0.y);    // step 0 -> buffer 0
        tb2[0][pstg1] = make_float2(p0.z, p0.w);
        p0 = psrc[1 * 256 + t256];                  // step 1 (in flight)
        p1 = psrc[2 * 256 + t256];                  // step 2 (in flight)
    }
    wg_barrier();

    // ---- Exclusive shift (DPP) + wave1 prepends wave0's totals ----
    {
        float xt[8];
#pragma unroll
        for (int n = 0; n < 8; ++n) xt[n] = xw_s[r][h * 8 + n];
        const float ss1 = DPPF(0x111, 0xF, ss);
        const float ssb = DPPF(0x142, 0xA, ss);
        const float sse = (c == 16) ? ssb : ss1;   // exclusive dtp-prefix
#pragma unroll
        for (int n = 0; n < 8; ++n) {
            const float x1 = DPPF(0x111, 0xF, x[n]);
            const float xb = DPPF(0x142, 0xA, x[n]);
            const float xe = (c == 16) ? xb : x1;  // exclusive within wave
            x[n] = W ? fmaf(EXP2(A2[n] * sse), xt[n], xe) : xe;
        }
    }

    // repack for pass 2
#pragma unroll
    for (int q = 0; q < 4; ++q) { x2[q].x = x[2 * q]; x2[q].y = x[2 * q + 1]; }

    // ---- Pass 2: rescan; 16 one-step epochs, depth-2 prefetch, pk math ----
    const float Dd = D_g[d];
    if (XF) {
#pragma unroll
        for (int i = 0; i < CL; ++i) {
            const unsigned duw = du_s[lb + i * ISTR2 + cg];
            const float dtp = __builtin_bit_cast(float, duw & 0xFFFF0000u);
            const float uu = __builtin_bit_cast(float, duw << 16);
            const float dtu = dtp * uu;
            f32x2 qb[4], qc[4];
            qb[0] = *reinterpret_cast<const f32x2*>(&tb2[i & 1][trb]);
            qb[1] = *reinterpret_cast<const f32x2*>(&tb2[i & 1][trb + 65]);
            qb[2] = *reinterpret_cast<const f32x2*>(&tb2[i & 1][trb + 130]);
            qb[3] = *reinterpret_cast<const f32x2*>(&tb2[i & 1][trb + 195]);
            qc[0] = *reinterpret_cast<const f32x2*>(&tb2[i & 1][TS2 + trb]);
            qc[1] = *reinterpret_cast<const f32x2*>(&tb2[i & 1][TS2 + trb + 65]);
            qc[2] = *reinterpret_cast<const f32x2*>(&tb2[i & 1][TS2 + trb + 130]);
            qc[3] = *reinterpret_cast<const f32x2*>(&tb2[i & 1][TS2 + trb + 195]);
            f32x2 dd; dd.x = dtp; dd.y = dtp;
            f32x2 uu2; uu2.x = dtu; uu2.y = dtu;
            f32x2 acc2; acc2.x = 0.f; acc2.y = 0.f;
#pragma unroll
            for (int q = 0; q < 4; ++q) {
                const f32x2 tq = dd * A2p[q];
                f32x2 e; e.x = EXP2(tq.x); e.y = EXP2(tq.y);
                const f32x2 db = uu2 * qb[q];
                x2[q] = pk_fma(e, x2[q], db);
                acc2 = pk_fma(x2[q], qc[q], acc2);
            }
            float acc = acc2.x + acc2.y;
            acc += __shfl_xor(acc, 32, 64);        // both halves get full sum
            const float yv = fmaf(uu, Dd, acc);
            y[i & 7] = ((i >> 3) == h) ? yv : y[i & 7];   // static idx
            if (i + 1 < CL) {                      // write step i+1 tile
                const float4 pv = (i & 1) ? p1 : p0;
                tb2[(i + 1) & 1][pstg0] = make_float2(pv.x, pv.y);
                tb2[(i + 1) & 1][pstg1] = make_float2(pv.z, pv.w);
            }
            if (i + 3 < CL) {                      // issue step i+3
                if (i & 1) p1 = psrc[(i + 3) * 256 + t256];
                else       p0 = psrc[(i + 3) * 256 + t256];
            }
            if (i + 1 < CL) wg_barrier();
        }
    } else {
#pragma unroll
        for (int i = 0; i < CL; ++i) {
            const unsigned duw = du_s[lb + i * ISTR2 + cg];
            const float dtp = __builtin_bit_cast(float, duw & 0xFFFF0000u);
            const float uu = __builtin_bit_cast(float, duw << 16);
            const float dtu = dtp * uu;
            const int l = cg * CL + i;
            const int k0 = 2 * h;
            float bv[8], cv[8];
#pragma unroll
            for (int q = 0; q < 8; ++q) {
                bv[q] = B_g[(size_t)(b * N + 4 * k0 + q) * L + l];
                cv[q] = C_g[(size_t)(b * N + 4 * k0 + q) * L + l];
            }
            float acc = 0.f;
#pragma unroll
            for (int n = 0; n < 8; ++n) {
                const float a = EXP2(dtp * A2[n]);
                const float xs = (n & 1) ? x2[n >> 1].y : x2[n >> 1].x;
                const float xn = fmaf(a, xs, dtu * bv[n]);
                if (n & 1) x2[n >> 1].y = xn; else x2[n >> 1].x = xn;
                acc = fmaf(xn, cv[n], acc);
            }
            acc += __shfl_xor(acc, 32, 64);
            const float yv = fmaf(uu, Dd, acc);
            y[i & 7] = ((i >> 3) == h) ? yv : y[i & 7];
        }
    }

    // ---- Epilogue: per-lane z read (32B), silu gate, y store from regs ----
    {
        const size_t gz = (size_t)row * L + cg * CL + h * 8;
        const float4 z0 = *reinterpret_cast<const float4*>(&z_g[gz]);
        const float4 z1 = *reinterpret_cast<const float4*>(&z_g[gz + 4]);
        float out[8];
#pragma unroll
        for (int j = 0; j < 8; ++j) {
            const float zv = (j < 4) ? (&z0.x)[j] : (&z1.x)[j - 4];
            const float e = EXP2(-zv * LOG2E);
            const float sig = __builtin_amdgcn_rcpf(1.f + e);
            out[j] = y[j] * (zv * sig);
        }
        *reinterpret_cast<float4*>(&y_g[gz]) =
            make_float4(out[0], out[1], out[2], out[3]);
        *reinterpret_cast<float4*>(&y_g[gz + 4]) =
            make_float4(out[4], out[5], out[6], out[7]);
    }
}

extern "C" void kernel_launch(void* const* d_in, const int* in_sizes, int n_in,
                              void* d_out, int out_size, void* d_ws, size_t ws_size,
                              hipStream_t stream) {
    const float* u     = (const float*)d_in[0];
    const float* delta = (const float*)d_in[1];
    const float* A     = (const float*)d_in[2];
    const float* B     = (const float*)d_in[3];
    const float* C     = (const float*)d_in[4];
    const float* D     = (const float*)d_in[5];
    const float* z     = (const float*)d_in[6];
    const float* bias  = (const float*)d_in[7];
    const int*   sp    = (const int*)d_in[8];
    float* y = (float*)d_out;

    const size_t bc_bytes = (size_t)Bsz * 4096 * sizeof(float4);  // 128 KB each
    const bool xf = ws_size >= 2 * bc_bytes;
    float4* Bs = (float4*)d_ws;
    float4* Cs = (float4*)((char*)d_ws + bc_bytes);

    if (xf) {
        transform_bc_kernel<<<dim3(16, Bsz, 2), 256, 0, stream>>>(B, C, Bs, Cs);
        mamba_scan25_kernel<true><<<dim3((Bsz * Dm) / RPB), TPB, 0, stream>>>(
            u, delta, A, B, C, Bs, Cs, D, z, bias, sp, y);
    } else {
        mamba_scan25_kernel<false><<<dim3((Bsz * Dm) / RPB), TPB, 0, stream>>>(
            u, delta, A, B, C, Bs, Cs, D, z, bias, sp, y);
    }
}

// Round 21
// 176.407 us; speedup vs baseline: 1.9408x; 1.9408x over previous
//
#include <hip/hip_runtime.h>
#include <math.h>

// Mamba selective scan:
//   u, delta, z : (2, 2048, 1024) f32 ; A : (2048, 16) f32
//   B, C : (2, 16, 1024) f32 ; D, delta_bias : (2048,) f32 ; softplus flag
// Output y : (2, 2048, 1024) f32
//
// v26 = v24 (bf16-packed du_s, LDS 33.8 KB; all math harness-verified)
//       + __launch_bounds__(512, 4).
//   r20 post-mortem: (512,8) produced a 32-VGPR cap (not 64) -> massive
//   spill (WRITE 790 MB, 342 us). Empirical mapping: cap = 256/w (gfx950
//   unified VGPR/AGPR budget), so w=4 -> 64-reg cap = exactly the
//   allocation v23 reached naturally without spilling. With VGPR<=64 and
//   LDS 33.8<=40 KB, 4 blocks/CU = 32 waves resident, grid 1024 = 4x256
//   tiles evenly -> no serialized tail (r18 theory, clean test).
//   Tripwires: VGPR == 64 (mapping check), WRITE_SIZE == 16384 KB
//   (spill check -> fallback v23 @43.2us), absmax <= 0.5.
constexpr int Bsz = 2, Dm = 2048, L = 1024, N = 16;
constexpr int CL = 16;          // chunk length (steps per lane)
constexpr int WPR = 2;          // waves per row
constexpr int RPB = 4;          // rows per block
constexpr int TPB = RPB * WPR * 64;  // 512
constexpr int NT = 8;           // pass-1 tiles (2 steps each)
constexpr int ISTR2 = 65;       // du_s u32 stride per step (64 + 1 pad)
constexpr int LROW2 = CL * ISTR2;    // 1040 u32 per row
constexpr int TS2 = 8 * 65;     // 520 float2: one step-group (8 j-rows x 65)
constexpr float LOG2E = 1.4426950408889634f;
constexpr float RLOG2E = 0.6931471805599453f;   // ln 2

#define EXP2(x) __builtin_amdgcn_exp2f(x)

typedef __attribute__((ext_vector_type(2))) float f32x2;

__device__ __forceinline__ f32x2 pk_fma(f32x2 a, f32x2 b, f32x2 c) {
    return __builtin_elementwise_fma(a, b, c);
}

// bf16 round-to-nearest-even (returns the high 16 bits)
__device__ __forceinline__ unsigned bf16_rn(float f) {
    const unsigned u = __builtin_bit_cast(unsigned, f);
    return (u + 0x7FFFu + ((u >> 16) & 1u)) >> 16;
}

// DPP lane-shift on the VALU pipe; masked/invalid lanes receive old = 0
// (identity for the affine scan). ctrl: 0x111=row_shr:1 0x112=row_shr:2
// 0x114=row_shr:4 0x118=row_shr:8 0x142=row_bcast:15.
#define DPPF(CTRL, RM, v) __builtin_bit_cast(float, __builtin_amdgcn_update_dpp( \
        0, __builtin_bit_cast(int, (float)(v)), (CTRL), (RM), 0xF, false))

// One affine-scan stage over (ss, x[8]) with window-decay exp2(A2[n]*ss).
// r9-verified machinery (absmax-clean), incl. the 0xA mask on row_bcast.
#define COMBINE_STAGE(CTRL, RM) do {                                      \
    const float ssp_ = DPPF(CTRL, RM, ss);                                \
    float xp_[8];                                                         \
    _Pragma("unroll") for (int n_ = 0; n_ < 8; ++n_)                      \
        xp_[n_] = DPPF(CTRL, RM, x[n_]);                                  \
    _Pragma("unroll") for (int n_ = 0; n_ < 8; ++n_)                      \
        x[n_] = fmaf(EXP2(A2[n_] * ss), xp_[n_], x[n_]);                  \
    ss += ssp_;                                                           \
} while (0)

// Workgroup barrier WITHOUT the vmcnt(0) drain __syncthreads inserts.
// lgkmcnt(0) makes this wave's LDS writes visible before the barrier;
// in-flight global->register loads keep counting across it.
__device__ __forceinline__ void wg_barrier() {
    asm volatile("s_waitcnt lgkmcnt(0)" ::: "memory");
    __builtin_amdgcn_s_barrier();
    asm volatile("" ::: "memory");
}

// ---------------------------------------------------------------------------
// Transform B,C into scan layout (chunk length 16), k-MAJOR:
//   Bs[b*4096 + i*256 + k*64 + cg] = float4 { B[b][4k+q][cg*16+i] } q=0..3
// Staging reads are then fully coalesced per tile.
// ---------------------------------------------------------------------------
__global__ __launch_bounds__(256) void transform_bc_kernel(
    const float* __restrict__ B_g, const float* __restrict__ C_g,
    float4* __restrict__ Bs, float4* __restrict__ Cs)
{
    const int o = threadIdx.x + 256 * blockIdx.x;   // 4096 float4 per (b, src)
    const int b = blockIdx.y;
    const float* __restrict__ src = blockIdx.z ? C_g : B_g;
    float4* __restrict__ dst = blockIdx.z ? Cs : Bs;
    const int cg = o & 63, k = (o >> 6) & 3, i = o >> 8;
    const int l = cg * CL + i;
    float4 v;
    v.x = src[(size_t)(b * N + 4 * k + 0) * L + l];
    v.y = src[(size_t)(b * N + 4 * k + 1) * L + l];
    v.z = src[(size_t)(b * N + 4 * k + 2) * L + l];
    v.w = src[(size_t)(b * N + 4 * k + 3) * L + l];
    dst[(size_t)b * 4096 + o] = v;
}

// ---------------------------------------------------------------------------
// Scan kernel. 8 waves/block = 4 rows x 2 waves. Wave handles 32 chunks of
// 16 steps. lane = h*32 + c: h = n-half, c = chunk-in-wave. cg = W*32+c.
// B/C tiles shared by all 4 rows via LDS (b64 conflict-free layout).
// ---------------------------------------------------------------------------
template<bool XF>
__global__ __launch_bounds__(TPB, 4) void mamba_scan26_kernel(
    const float* __restrict__ u_g, const float* __restrict__ delta_g,
    const float* __restrict__ A_g,
    const float* __restrict__ B_g, const float* __restrict__ C_g,
    const float4* __restrict__ Bs, const float4* __restrict__ Cs,
    const float* __restrict__ D_g, const float* __restrict__ z_g,
    const float* __restrict__ bias_g, const int* __restrict__ sp_g,
    float* __restrict__ y_g)
{
    __shared__ unsigned du_s[RPB * LROW2];  // [r][i*65+cg] = bf16(dtp)<<16|bf16(u)
    __shared__ float2 tb2[2][2 * TS2];      // 16.6 KB tile ping-pong buffers
    __shared__ float xw_s[RPB][16];         // per-row wave0 totals

    const int tid = threadIdx.x;
    const int wid = tid >> 6;                  // wave id 0..7
    const int lane = tid & 63;
    const int W = wid & 1;                     // wave-in-row
    const int r = wid >> 1;                    // local row 0..3
    const int h = lane >> 5;                   // n-half
    const int c = lane & 31;                   // chunk-in-wave
    const int cg = W * 32 + c;                 // global chunk 0..63
    const int row = blockIdx.x * RPB + r;
    const int b = row >> 11;                   // row / Dm (blocks never straddle)
    const int d = row & (Dm - 1);
    const size_t Bb = (size_t)b * 4096;        // workspace base (float4 units)
    const int lb = r * LROW2;
    const int t128 = tid & 127;                // thread-in-row (2 waves)
    // pass-1 staging: wave wid owns (il = wid>>2, k = wid&3) for all 64 cg
    const int stg0 = (wid >> 2) * TS2 + (2 * (wid & 3)) * 65 + lane;
    const int stg1 = stg0 + 65;
    // pass-2 staging: threads 0-255 stage B, 256-511 stage C (1 step each)
    const int bc = tid >> 8;
    const int t256 = tid & 255;
    const int pstg0 = bc * TS2 + (2 * ((t256 >> 6) & 3)) * 65 + (t256 & 63);
    const int pstg1 = pstg0 + 65;
    const float4* __restrict__ psrc = (bc ? Cs : Bs) + Bb;
    // tile read base for this lane: j = 4h at column cg
    const int trb = (4 * h) * 65 + cg;

    float4 s0, s1;
    if (XF) s0 = Bs[Bb + tid];                 // pass-1 tile 0, issued early

    // ---- Phase 0: coalesced load of delta/u -> step-major packed LDS ----
    {
        const float bias = bias_g[d];
        const int sp = sp_g[0];
#pragma unroll
        for (int p = 0; p < 2; ++p) {
            const int l0 = 4 * t128 + 512 * p;
            const size_t gb = (size_t)row * L + l0;
            const float4 d4 = *reinterpret_cast<const float4*>(&delta_g[gb]);
            const float4 u4 = *reinterpret_cast<const float4*>(&u_g[gb]);
#pragma unroll
            for (int k = 0; k < 4; ++k) {
                const int li = l0 + k;
                const float t = (&d4.x)[k] + bias;
                // softplus: max(t,0) + ln(1 + 2^(-|t|*log2e))
                const float e = EXP2(-fabsf(t) * LOG2E);
                const float p_ = sp ? (fmaxf(t, 0.f) +
                                       __builtin_amdgcn_logf(1.f + e) * RLOG2E)
                                    : t;
                const int a = (li & (CL - 1)) * ISTR2 + (li >> 4);
                du_s[lb + a] = (bf16_rn(p_) << 16) | bf16_rn((&u4.x)[k]);
            }
        }
    }
    float A2[8];
    f32x2 A2p[4];
#pragma unroll
    for (int g = 0; g < 2; ++g) {
        const float4 a4 = *reinterpret_cast<const float4*>(&A_g[d * N + h * 8 + g * 4]);
        A2[g * 4 + 0] = a4.x * LOG2E; A2[g * 4 + 1] = a4.y * LOG2E;
        A2[g * 4 + 2] = a4.z * LOG2E; A2[g * 4 + 3] = a4.w * LOG2E;
    }
#pragma unroll
    for (int q = 0; q < 4; ++q) { A2p[q].x = A2[2 * q]; A2p[q].y = A2[2 * q + 1]; }
    if (XF) {
        tb2[0][stg0] = make_float2(s0.x, s0.y);     // stage tile 0
        tb2[0][stg1] = make_float2(s0.z, s0.w);
        s0 = Bs[Bb + 512 + tid];                    // tile 1 (in flight)
        s1 = Bs[Bb + 1024 + tid];                   // tile 2 (in flight)
    }
    wg_barrier();

    // ---- Pass 1: zero-init scan; 8 epochs, depth-2 prefetch, pk math ----
    f32x2 x2[4];
#pragma unroll
    for (int q = 0; q < 4; ++q) { x2[q].x = 0.f; x2[q].y = 0.f; }
    float y[8];
#pragma unroll
    for (int n = 0; n < 8; ++n) y[n] = 0.f;
    float ss = 0.f;

    if (XF) {
#pragma unroll
        for (int t = 0; t < NT; ++t) {
#pragma unroll
            for (int il = 0; il < 2; ++il) {
                const int i = 2 * t + il;
                const unsigned duw = du_s[lb + i * ISTR2 + cg];
                const float dtp = __builtin_bit_cast(float, duw & 0xFFFF0000u);
                const float uu = __builtin_bit_cast(float, duw << 16);
                const float dtu = dtp * uu;
                ss += dtp;
                const int rb = il * TS2 + trb;
                f32x2 qv[4];
                qv[0] = *reinterpret_cast<const f32x2*>(&tb2[t & 1][rb]);
                qv[1] = *reinterpret_cast<const f32x2*>(&tb2[t & 1][rb + 65]);
                qv[2] = *reinterpret_cast<const f32x2*>(&tb2[t & 1][rb + 130]);
                qv[3] = *reinterpret_cast<const f32x2*>(&tb2[t & 1][rb + 195]);
                f32x2 dd; dd.x = dtp; dd.y = dtp;
                f32x2 uu2; uu2.x = dtu; uu2.y = dtu;
#pragma unroll
                for (int q = 0; q < 4; ++q) {
                    const f32x2 tq = dd * A2p[q];
                    f32x2 e; e.x = EXP2(tq.x); e.y = EXP2(tq.y);
                    const f32x2 db = uu2 * qv[q];
                    x2[q] = pk_fma(e, x2[q], db);
                }
            }
            if (t + 1 < NT) {                       // write tile t+1
                const float4 sv = (t & 1) ? s1 : s0;
                tb2[(t + 1) & 1][stg0] = make_float2(sv.x, sv.y);
                tb2[(t + 1) & 1][stg1] = make_float2(sv.z, sv.w);
            }
            if (t + 3 < NT) {                       // issue tile t+3
                if (t & 1) s1 = Bs[Bb + (t + 3) * 512 + tid];
                else       s0 = Bs[Bb + (t + 3) * 512 + tid];
            }
            if (t + 1 < NT) wg_barrier();
        }
    } else {
#pragma unroll
        for (int i = 0; i < CL; ++i) {
            const unsigned duw = du_s[lb + i * ISTR2 + cg];
            const float dtp = __builtin_bit_cast(float, duw & 0xFFFF0000u);
            const float uu = __builtin_bit_cast(float, duw << 16);
            const float dtu = dtp * uu;
            ss += dtp;
            const int l = cg * CL + i;
            const int k0 = 2 * h;
            float4 B0, B1;
#pragma unroll
            for (int q = 0; q < 4; ++q) {
                (&B0.x)[q] = B_g[(size_t)(b * N + 4 * k0 + q) * L + l];
                (&B1.x)[q] = B_g[(size_t)(b * N + 4 * k0 + 4 + q) * L + l];
            }
            const float bv[8] = {B0.x, B0.y, B0.z, B0.w, B1.x, B1.y, B1.z, B1.w};
#pragma unroll
            for (int n = 0; n < 8; ++n) {
                const float a = EXP2(dtp * A2[n]);
                const float xs = (n & 1) ? x2[n >> 1].y : x2[n >> 1].x;
                const float xn = fmaf(a, xs, dtu * bv[n]);
                if (n & 1) x2[n >> 1].y = xn; else x2[n >> 1].x = xn;
            }
        }
    }

    // unpack to scalars for the combine
    float x[8];
#pragma unroll
    for (int q = 0; q < 4; ++q) { x[2 * q] = x2[q].x; x[2 * q + 1] = x2[q].y; }

    // issue pass-2 step 0 load (latency hides under the combine)
    float4 p0, p1;
    if (XF) p0 = psrc[t256];

    // ---- Combine level 1: 32-lane segmented affine scan via DPP ----
    // After: x[n] = inclusive chunk-combine over [seg_start..c];
    //        ss   = inclusive dtp-prefix over the same window.
    COMBINE_STAGE(0x111, 0xF);   // row_shr:1
    COMBINE_STAGE(0x112, 0xF);   // row_shr:2
    COMBINE_STAGE(0x114, 0xF);   // row_shr:4
    COMBINE_STAGE(0x118, 0xF);   // row_shr:8
    COMBINE_STAGE(0x142, 0xA);   // row_bcast:15 -> rows 1,3 ONLY (r8 bug fix)

    // ---- Combine level 2 publish + stage pass-2 step 0; ONE barrier ----
    if (W == 0 && c == 31) {
#pragma unroll
        for (int n = 0; n < 8; ++n) xw_s[r][h * 8 + n] = x[n];
    }
    if (XF) {
        tb2[0][pstg0] = make_float2(p0.x, p0.y);    // step 0 -> buffer 0
        tb2[0][pstg1] = make_float2(p0.z, p0.w);
        p0 = psrc[1 * 256 + t256];                  // step 1 (in flight)
        p1 = psrc[2 * 256 + t256];                  // step 2 (in flight)
    }
    wg_barrier();

    // ---- Exclusive shift (DPP) + wave1 prepends wave0's totals ----
    {
        float xt[8];
#pragma unroll
        for (int n = 0; n < 8; ++n) xt[n] = xw_s[r][h * 8 + n];
        const float ss1 = DPPF(0x111, 0xF, ss);
        const float ssb = DPPF(0x142, 0xA, ss);
        const float sse = (c == 16) ? ssb : ss1;   // exclusive dtp-prefix
#pragma unroll
        for (int n = 0; n < 8; ++n) {
            const float x1 = DPPF(0x111, 0xF, x[n]);
            const float xb = DPPF(0x142, 0xA, x[n]);
            const float xe = (c == 16) ? xb : x1;  // exclusive within wave
            x[n] = W ? fmaf(EXP2(A2[n] * sse), xt[n], xe) : xe;
        }
    }

    // repack for pass 2
#pragma unroll
    for (int q = 0; q < 4; ++q) { x2[q].x = x[2 * q]; x2[q].y = x[2 * q + 1]; }

    // ---- Pass 2: rescan; 16 one-step epochs, depth-2 prefetch, pk math ----
    const float Dd = D_g[d];
    if (XF) {
#pragma unroll
        for (int i = 0; i < CL; ++i) {
            const unsigned duw = du_s[lb + i * ISTR2 + cg];
            const float dtp = __builtin_bit_cast(float, duw & 0xFFFF0000u);
            const float uu = __builtin_bit_cast(float, duw << 16);
            const float dtu = dtp * uu;
            f32x2 qb[4], qc[4];
            qb[0] = *reinterpret_cast<const f32x2*>(&tb2[i & 1][trb]);
            qb[1] = *reinterpret_cast<const f32x2*>(&tb2[i & 1][trb + 65]);
            qb[2] = *reinterpret_cast<const f32x2*>(&tb2[i & 1][trb + 130]);
            qb[3] = *reinterpret_cast<const f32x2*>(&tb2[i & 1][trb + 195]);
            qc[0] = *reinterpret_cast<const f32x2*>(&tb2[i & 1][TS2 + trb]);
            qc[1] = *reinterpret_cast<const f32x2*>(&tb2[i & 1][TS2 + trb + 65]);
            qc[2] = *reinterpret_cast<const f32x2*>(&tb2[i & 1][TS2 + trb + 130]);
            qc[3] = *reinterpret_cast<const f32x2*>(&tb2[i & 1][TS2 + trb + 195]);
            f32x2 dd; dd.x = dtp; dd.y = dtp;
            f32x2 uu2; uu2.x = dtu; uu2.y = dtu;
            f32x2 acc2; acc2.x = 0.f; acc2.y = 0.f;
#pragma unroll
            for (int q = 0; q < 4; ++q) {
                const f32x2 tq = dd * A2p[q];
                f32x2 e; e.x = EXP2(tq.x); e.y = EXP2(tq.y);
                const f32x2 db = uu2 * qb[q];
                x2[q] = pk_fma(e, x2[q], db);
                acc2 = pk_fma(x2[q], qc[q], acc2);
            }
            float acc = acc2.x + acc2.y;
            acc += __shfl_xor(acc, 32, 64);        // both halves get full sum
            const float yv = fmaf(uu, Dd, acc);
            y[i & 7] = ((i >> 3) == h) ? yv : y[i & 7];   // static idx
            if (i + 1 < CL) {                      // write step i+1 tile
                const float4 pv = (i & 1) ? p1 : p0;
                tb2[(i + 1) & 1][pstg0] = make_float2(pv.x, pv.y);
                tb2[(i + 1) & 1][pstg1] = make_float2(pv.z, pv.w);
            }
            if (i + 3 < CL) {                      // issue step i+3
                if (i & 1) p1 = psrc[(i + 3) * 256 + t256];
                else       p0 = psrc[(i + 3) * 256 + t256];
            }
            if (i + 1 < CL) wg_barrier();
        }
    } else {
#pragma unroll
        for (int i = 0; i < CL; ++i) {
            const unsigned duw = du_s[lb + i * ISTR2 + cg];
            const float dtp = __builtin_bit_cast(float, duw & 0xFFFF0000u);
            const float uu = __builtin_bit_cast(float, duw << 16);
            const float dtu = dtp * uu;
            const int l = cg * CL + i;
            const int k0 = 2 * h;
            float bv[8], cv[8];
#pragma unroll
            for (int q = 0; q < 8; ++q) {
                bv[q] = B_g[(size_t)(b * N + 4 * k0 + q) * L + l];
                cv[q] = C_g[(size_t)(b * N + 4 * k0 + q) * L + l];
            }
            float acc = 0.f;
#pragma unroll
            for (int n = 0; n < 8; ++n) {
                const float a = EXP2(dtp * A2[n]);
                const float xs = (n & 1) ? x2[n >> 1].y : x2[n >> 1].x;
                const float xn = fmaf(a, xs, dtu * bv[n]);
                if (n & 1) x2[n >> 1].y = xn; else x2[n >> 1].x = xn;
                acc = fmaf(xn, cv[n], acc);
            }
            acc += __shfl_xor(acc, 32, 64);
            const float yv = fmaf(uu, Dd, acc);
            y[i & 7] = ((i >> 3) == h) ? yv : y[i & 7];
        }
    }

    // ---- Epilogue: per-lane z read (32B), silu gate, y store from regs ----
    {
        const size_t gz = (size_t)row * L + cg * CL + h * 8;
        const float4 z0 = *reinterpret_cast<const float4*>(&z_g[gz]);
        const float4 z1 = *reinterpret_cast<const float4*>(&z_g[gz + 4]);
        float out[8];
#pragma unroll
        for (int j = 0; j < 8; ++j) {
            const float zv = (j < 4) ? (&z0.x)[j] : (&z1.x)[j - 4];
            const float e = EXP2(-zv * LOG2E);
            const float sig = __builtin_amdgcn_rcpf(1.f + e);
            out[j] = y[j] * (zv * sig);
        }
        *reinterpret_cast<float4*>(&y_g[gz]) =
            make_float4(out[0], out[1], out[2], out[3]);
        *reinterpret_cast<float4*>(&y_g[gz + 4]) =
            make_float4(out[4], out[5], out[6], out[7]);
    }
}

extern "C" void kernel_launch(void* const* d_in, const int* in_sizes, int n_in,
                              void* d_out, int out_size, void* d_ws, size_t ws_size,
                              hipStream_t stream) {
    const float* u     = (const float*)d_in[0];
    const float* delta = (const float*)d_in[1];
    const float* A     = (const float*)d_in[2];
    const float* B     = (const float*)d_in[3];
    const float* C     = (const float*)d_in[4];
    const float* D     = (const float*)d_in[5];
    const float* z     = (const float*)d_in[6];
    const float* bias  = (const float*)d_in[7];
    const int*   sp    = (const int*)d_in[8];
    float* y = (float*)d_out;

    const size_t bc_bytes = (size_t)Bsz * 4096 * sizeof(float4);  // 128 KB each
    const bool xf = ws_size >= 2 * bc_bytes;
    float4* Bs = (float4*)d_ws;
    float4* Cs = (float4*)((char*)d_ws + bc_bytes);

    if (xf) {
        transform_bc_kernel<<<dim3(16, Bsz, 2), 256, 0, stream>>>(B, C, Bs, Cs);
        mamba_scan26_kernel<true><<<dim3((Bsz * Dm) / RPB), TPB, 0, stream>>>(
            u, delta, A, B, C, Bs, Cs, D, z, bias, sp, y);
    } else {
        mamba_scan26_kernel<false><<<dim3((Bsz * Dm) / RPB), TPB, 0, stream>>>(
            u, delta, A, B, C, Bs, Cs, D, z, bias, sp, y);
    }
}

// Round 22
// 42.695 us; speedup vs baseline: 8.0189x; 4.1318x over previous
//
#include <hip/hip_runtime.h>
#include <math.h>

// Mamba selective scan:
//   u, delta, z : (2, 2048, 1024) f32 ; A : (2048, 16) f32
//   B, C : (2, 16, 1024) f32 ; D, delta_bias : (2048,) f32 ; softplus flag
// Output y : (2, 2048, 1024) f32
//
// v27 = v23 RESTORED VERBATIM (43.2 us, best verified).
//   r19-r21 post-mortems close the residency direction by arithmetic:
//   4 blocks/CU needs LDS<=40.96KB AND VGPR<=64 simultaneously; the f32-du
//   variant fits regs (64 natural) but not LDS (50.2KB); the bf16-du
//   variant fits LDS (33.8KB) but not regs (128 natural, spills under a
//   64 cap -- r21: WRITE 473MB). No feasible config exists.
//   v23's stack (all harness-verified):
//   - RPB=4 B/C LDS tiles (L2 traffic /4, r10 win)
//   - b64 conflict-free tile layout (conflicts -> 0)
//   - non-draining wg_barrier + depth-2 epoch prefetch
//   - packed-f32 (v_pk_*) pass math via native v2f32 (r16 win)
//   - scalar-ss DPP affine combine, P[8] eliminated (r18 win)
//   - y-in-regs epilogue
constexpr int Bsz = 2, Dm = 2048, L = 1024, N = 16;
constexpr int CL = 16;          // chunk length (steps per lane)
constexpr int WPR = 2;          // waves per row
constexpr int RPB = 4;          // rows per block
constexpr int TPB = RPB * WPR * 64;  // 512
constexpr int NT = 8;           // pass-1 tiles (2 steps each)
constexpr int ISTR2 = 65;       // du_s float2 stride per step (64 + 1 pad)
constexpr int LROW2 = CL * ISTR2;    // 1040 float2 per row
constexpr int TS2 = 8 * 65;     // 520 float2: one step-group (8 j-rows x 65)
constexpr float LOG2E = 1.4426950408889634f;
constexpr float RLOG2E = 0.6931471805599453f;   // ln 2

#define EXP2(x) __builtin_amdgcn_exp2f(x)

typedef __attribute__((ext_vector_type(2))) float f32x2;

__device__ __forceinline__ f32x2 pk_fma(f32x2 a, f32x2 b, f32x2 c) {
    return __builtin_elementwise_fma(a, b, c);
}

// DPP lane-shift on the VALU pipe; masked/invalid lanes receive old = 0
// (identity for the affine scan). ctrl: 0x111=row_shr:1 0x112=row_shr:2
// 0x114=row_shr:4 0x118=row_shr:8 0x142=row_bcast:15.
#define DPPF(CTRL, RM, v) __builtin_bit_cast(float, __builtin_amdgcn_update_dpp( \
        0, __builtin_bit_cast(int, (float)(v)), (CTRL), (RM), 0xF, false))

// One affine-scan stage over (ss, x[8]) with window-decay exp2(A2[n]*ss).
// r9-verified machinery (absmax-clean), incl. the 0xA mask on row_bcast.
#define COMBINE_STAGE(CTRL, RM) do {                                      \
    const float ssp_ = DPPF(CTRL, RM, ss);                                \
    float xp_[8];                                                         \
    _Pragma("unroll") for (int n_ = 0; n_ < 8; ++n_)                      \
        xp_[n_] = DPPF(CTRL, RM, x[n_]);                                  \
    _Pragma("unroll") for (int n_ = 0; n_ < 8; ++n_)                      \
        x[n_] = fmaf(EXP2(A2[n_] * ss), xp_[n_], x[n_]);                  \
    ss += ssp_;                                                           \
} while (0)

// Workgroup barrier WITHOUT the vmcnt(0) drain __syncthreads inserts.
// lgkmcnt(0) makes this wave's LDS writes visible before the barrier;
// in-flight global->register loads keep counting across it.
__device__ __forceinline__ void wg_barrier() {
    asm volatile("s_waitcnt lgkmcnt(0)" ::: "memory");
    __builtin_amdgcn_s_barrier();
    asm volatile("" ::: "memory");
}

// ---------------------------------------------------------------------------
// Transform B,C into scan layout (chunk length 16), k-MAJOR:
//   Bs[b*4096 + i*256 + k*64 + cg] = float4 { B[b][4k+q][cg*16+i] } q=0..3
// Staging reads are then fully coalesced per tile.
// ---------------------------------------------------------------------------
__global__ __launch_bounds__(256) void transform_bc_kernel(
    const float* __restrict__ B_g, const float* __restrict__ C_g,
    float4* __restrict__ Bs, float4* __restrict__ Cs)
{
    const int o = threadIdx.x + 256 * blockIdx.x;   // 4096 float4 per (b, src)
    const int b = blockIdx.y;
    const float* __restrict__ src = blockIdx.z ? C_g : B_g;
    float4* __restrict__ dst = blockIdx.z ? Cs : Bs;
    const int cg = o & 63, k = (o >> 6) & 3, i = o >> 8;
    const int l = cg * CL + i;
    float4 v;
    v.x = src[(size_t)(b * N + 4 * k + 0) * L + l];
    v.y = src[(size_t)(b * N + 4 * k + 1) * L + l];
    v.z = src[(size_t)(b * N + 4 * k + 2) * L + l];
    v.w = src[(size_t)(b * N + 4 * k + 3) * L + l];
    dst[(size_t)b * 4096 + o] = v;
}

// ---------------------------------------------------------------------------
// Scan kernel. 8 waves/block = 4 rows x 2 waves. Wave handles 32 chunks of
// 16 steps. lane = h*32 + c: h = n-half, c = chunk-in-wave. cg = W*32+c.
// B/C tiles shared by all 4 rows via LDS (b64 conflict-free layout).
// ---------------------------------------------------------------------------
template<bool XF>
__global__ __launch_bounds__(TPB) void mamba_scan27_kernel(
    const float* __restrict__ u_g, const float* __restrict__ delta_g,
    const float* __restrict__ A_g,
    const float* __restrict__ B_g, const float* __restrict__ C_g,
    const float4* __restrict__ Bs, const float4* __restrict__ Cs,
    const float* __restrict__ D_g, const float* __restrict__ z_g,
    const float* __restrict__ bias_g, const int* __restrict__ sp_g,
    float* __restrict__ y_g)
{
    __shared__ float2 du_s[RPB * LROW2];  // [r][i*65+cg] = (dtp,u)
    __shared__ float2 tb2[2][2 * TS2];    // 16.6 KB tile ping-pong buffers
    __shared__ float xw_s[RPB][16];       // per-row wave0 totals

    const int tid = threadIdx.x;
    const int wid = tid >> 6;                  // wave id 0..7
    const int lane = tid & 63;
    const int W = wid & 1;                     // wave-in-row
    const int r = wid >> 1;                    // local row 0..3
    const int h = lane >> 5;                   // n-half
    const int c = lane & 31;                   // chunk-in-wave
    const int cg = W * 32 + c;                 // global chunk 0..63
    const int row = blockIdx.x * RPB + r;
    const int b = row >> 11;                   // row / Dm (blocks never straddle)
    const int d = row & (Dm - 1);
    const size_t Bb = (size_t)b * 4096;        // workspace base (float4 units)
    const int lb = r * LROW2;
    const int t128 = tid & 127;                // thread-in-row (2 waves)
    // pass-1 staging: wave wid owns (il = wid>>2, k = wid&3) for all 64 cg
    const int stg0 = (wid >> 2) * TS2 + (2 * (wid & 3)) * 65 + lane;
    const int stg1 = stg0 + 65;
    // pass-2 staging: threads 0-255 stage B, 256-511 stage C (1 step each)
    const int bc = tid >> 8;
    const int t256 = tid & 255;
    const int pstg0 = bc * TS2 + (2 * ((t256 >> 6) & 3)) * 65 + (t256 & 63);
    const int pstg1 = pstg0 + 65;
    const float4* __restrict__ psrc = (bc ? Cs : Bs) + Bb;
    // tile read base for this lane: j = 4h at column cg
    const int trb = (4 * h) * 65 + cg;

    float4 s0, s1;
    if (XF) s0 = Bs[Bb + tid];                 // pass-1 tile 0, issued early

    // ---- Phase 0: coalesced load of delta/u -> step-major packed LDS ----
    {
        const float bias = bias_g[d];
        const int sp = sp_g[0];
#pragma unroll
        for (int p = 0; p < 2; ++p) {
            const int l0 = 4 * t128 + 512 * p;
            const size_t gb = (size_t)row * L + l0;
            const float4 d4 = *reinterpret_cast<const float4*>(&delta_g[gb]);
            const float4 u4 = *reinterpret_cast<const float4*>(&u_g[gb]);
#pragma unroll
            for (int k = 0; k < 4; ++k) {
                const int li = l0 + k;
                const float t = (&d4.x)[k] + bias;
                // softplus: max(t,0) + ln(1 + 2^(-|t|*log2e))
                const float e = EXP2(-fabsf(t) * LOG2E);
                const float p_ = sp ? (fmaxf(t, 0.f) +
                                       __builtin_amdgcn_logf(1.f + e) * RLOG2E)
                                    : t;
                const int a = (li & (CL - 1)) * ISTR2 + (li >> 4);
                du_s[lb + a] = make_float2(p_, (&u4.x)[k]);
            }
        }
    }
    float A2[8];
    f32x2 A2p[4];
#pragma unroll
    for (int g = 0; g < 2; ++g) {
        const float4 a4 = *reinterpret_cast<const float4*>(&A_g[d * N + h * 8 + g * 4]);
        A2[g * 4 + 0] = a4.x * LOG2E; A2[g * 4 + 1] = a4.y * LOG2E;
        A2[g * 4 + 2] = a4.z * LOG2E; A2[g * 4 + 3] = a4.w * LOG2E;
    }
#pragma unroll
    for (int q = 0; q < 4; ++q) { A2p[q].x = A2[2 * q]; A2p[q].y = A2[2 * q + 1]; }
    if (XF) {
        tb2[0][stg0] = make_float2(s0.x, s0.y);     // stage tile 0
        tb2[0][stg1] = make_float2(s0.z, s0.w);
        s0 = Bs[Bb + 512 + tid];                    // tile 1 (in flight)
        s1 = Bs[Bb + 1024 + tid];                   // tile 2 (in flight)
    }
    wg_barrier();

    // ---- Pass 1: zero-init scan; 8 epochs, depth-2 prefetch, pk math ----
    f32x2 x2[4];
#pragma unroll
    for (int q = 0; q < 4; ++q) { x2[q].x = 0.f; x2[q].y = 0.f; }
    float y[8];
#pragma unroll
    for (int n = 0; n < 8; ++n) y[n] = 0.f;
    float ss = 0.f;

    if (XF) {
#pragma unroll
        for (int t = 0; t < NT; ++t) {
#pragma unroll
            for (int il = 0; il < 2; ++il) {
                const int i = 2 * t + il;
                const float2 du = du_s[lb + i * ISTR2 + cg];
                const float dtp = du.x;
                const float dtu = du.x * du.y;
                ss += dtp;
                const int rb = il * TS2 + trb;
                f32x2 qv[4];
                qv[0] = *reinterpret_cast<const f32x2*>(&tb2[t & 1][rb]);
                qv[1] = *reinterpret_cast<const f32x2*>(&tb2[t & 1][rb + 65]);
                qv[2] = *reinterpret_cast<const f32x2*>(&tb2[t & 1][rb + 130]);
                qv[3] = *reinterpret_cast<const f32x2*>(&tb2[t & 1][rb + 195]);
                f32x2 dd; dd.x = dtp; dd.y = dtp;
                f32x2 uu2; uu2.x = dtu; uu2.y = dtu;
#pragma unroll
                for (int q = 0; q < 4; ++q) {
                    const f32x2 tq = dd * A2p[q];
                    f32x2 e; e.x = EXP2(tq.x); e.y = EXP2(tq.y);
                    const f32x2 db = uu2 * qv[q];
                    x2[q] = pk_fma(e, x2[q], db);
                }
            }
            if (t + 1 < NT) {                       // write tile t+1
                const float4 sv = (t & 1) ? s1 : s0;
                tb2[(t + 1) & 1][stg0] = make_float2(sv.x, sv.y);
                tb2[(t + 1) & 1][stg1] = make_float2(sv.z, sv.w);
            }
            if (t + 3 < NT) {                       // issue tile t+3
                if (t & 1) s1 = Bs[Bb + (t + 3) * 512 + tid];
                else       s0 = Bs[Bb + (t + 3) * 512 + tid];
            }
            if (t + 1 < NT) wg_barrier();
        }
    } else {
#pragma unroll
        for (int i = 0; i < CL; ++i) {
            const float2 du = du_s[lb + i * ISTR2 + cg];
            const float dtp = du.x;
            const float dtu = du.x * du.y;
            ss += dtp;
            const int l = cg * CL + i;
            const int k0 = 2 * h;
            float4 B0, B1;
#pragma unroll
            for (int q = 0; q < 4; ++q) {
                (&B0.x)[q] = B_g[(size_t)(b * N + 4 * k0 + q) * L + l];
                (&B1.x)[q] = B_g[(size_t)(b * N + 4 * k0 + 4 + q) * L + l];
            }
            const float bv[8] = {B0.x, B0.y, B0.z, B0.w, B1.x, B1.y, B1.z, B1.w};
#pragma unroll
            for (int n = 0; n < 8; ++n) {
                const float a = EXP2(dtp * A2[n]);
                const float xs = (n & 1) ? x2[n >> 1].y : x2[n >> 1].x;
                const float xn = fmaf(a, xs, dtu * bv[n]);
                if (n & 1) x2[n >> 1].y = xn; else x2[n >> 1].x = xn;
            }
        }
    }

    // unpack to scalars for the combine
    float x[8];
#pragma unroll
    for (int q = 0; q < 4; ++q) { x[2 * q] = x2[q].x; x[2 * q + 1] = x2[q].y; }

    // issue pass-2 step 0 load (latency hides under the combine)
    float4 p0, p1;
    if (XF) p0 = psrc[t256];

    // ---- Combine level 1: 32-lane segmented affine scan via DPP ----
    // After: x[n] = inclusive chunk-combine over [seg_start..c];
    //        ss   = inclusive dtp-prefix over the same window.
    COMBINE_STAGE(0x111, 0xF);   // row_shr:1
    COMBINE_STAGE(0x112, 0xF);   // row_shr:2
    COMBINE_STAGE(0x114, 0xF);   // row_shr:4
    COMBINE_STAGE(0x118, 0xF);   // row_shr:8
    COMBINE_STAGE(0x142, 0xA);   // row_bcast:15 -> rows 1,3 ONLY (r8 bug fix)

    // ---- Combine level 2 publish + stage pass-2 step 0; ONE barrier ----
    if (W == 0 && c == 31) {
#pragma unroll
        for (int n = 0; n < 8; ++n) xw_s[r][h * 8 + n] = x[n];
    }
    if (XF) {
        tb2[0][pstg0] = make_float2(p0.x, p0.y);    // step 0 -> buffer 0
        tb2[0][pstg1] = make_float2(p0.z, p0.w);
        p0 = psrc[1 * 256 + t256];                  // step 1 (in flight)
        p1 = psrc[2 * 256 + t256];                  // step 2 (in flight)
    }
    wg_barrier();

    // ---- Exclusive shift (DPP) + wave1 prepends wave0's totals ----
    {
        float xt[8];
#pragma unroll
        for (int n = 0; n < 8; ++n) xt[n] = xw_s[r][h * 8 + n];
        const float ss1 = DPPF(0x111, 0xF, ss);
        const float ssb = DPPF(0x142, 0xA, ss);
        const float sse = (c == 16) ? ssb : ss1;   // exclusive dtp-prefix
#pragma unroll
        for (int n = 0; n < 8; ++n) {
            const float x1 = DPPF(0x111, 0xF, x[n]);
            const float xb = DPPF(0x142, 0xA, x[n]);
            const float xe = (c == 16) ? xb : x1;  // exclusive within wave
            x[n] = W ? fmaf(EXP2(A2[n] * sse), xt[n], xe) : xe;
        }
    }

    // repack for pass 2
#pragma unroll
    for (int q = 0; q < 4; ++q) { x2[q].x = x[2 * q]; x2[q].y = x[2 * q + 1]; }

    // ---- Pass 2: rescan; 16 one-step epochs, depth-2 prefetch, pk math ----
    const float Dd = D_g[d];
    if (XF) {
#pragma unroll
        for (int i = 0; i < CL; ++i) {
            const float2 du = du_s[lb + i * ISTR2 + cg];
            const float dtp = du.x;
            const float uu = du.y;
            const float dtu = dtp * uu;
            f32x2 qb[4], qc[4];
            qb[0] = *reinterpret_cast<const f32x2*>(&tb2[i & 1][trb]);
            qb[1] = *reinterpret_cast<const f32x2*>(&tb2[i & 1][trb + 65]);
            qb[2] = *reinterpret_cast<const f32x2*>(&tb2[i & 1][trb + 130]);
            qb[3] = *reinterpret_cast<const f32x2*>(&tb2[i & 1][trb + 195]);
            qc[0] = *reinterpret_cast<const f32x2*>(&tb2[i & 1][TS2 + trb]);
            qc[1] = *reinterpret_cast<const f32x2*>(&tb2[i & 1][TS2 + trb + 65]);
            qc[2] = *reinterpret_cast<const f32x2*>(&tb2[i & 1][TS2 + trb + 130]);
            qc[3] = *reinterpret_cast<const f32x2*>(&tb2[i & 1][TS2 + trb + 195]);
            f32x2 dd; dd.x = dtp; dd.y = dtp;
            f32x2 uu2; uu2.x = dtu; uu2.y = dtu;
            f32x2 acc2; acc2.x = 0.f; acc2.y = 0.f;
#pragma unroll
            for (int q = 0; q < 4; ++q) {
                const f32x2 tq = dd * A2p[q];
                f32x2 e; e.x = EXP2(tq.x); e.y = EXP2(tq.y);
                const f32x2 db = uu2 * qb[q];
                x2[q] = pk_fma(e, x2[q], db);
                acc2 = pk_fma(x2[q], qc[q], acc2);
            }
            float acc = acc2.x + acc2.y;
            acc += __shfl_xor(acc, 32, 64);        // both halves get full sum
            const float yv = fmaf(uu, Dd, acc);
            y[i & 7] = ((i >> 3) == h) ? yv : y[i & 7];   // static idx
            if (i + 1 < CL) {                      // write step i+1 tile
                const float4 pv = (i & 1) ? p1 : p0;
                tb2[(i + 1) & 1][pstg0] = make_float2(pv.x, pv.y);
                tb2[(i + 1) & 1][pstg1] = make_float2(pv.z, pv.w);
            }
            if (i + 3 < CL) {                      // issue step i+3
                if (i & 1) p1 = psrc[(i + 3) * 256 + t256];
                else       p0 = psrc[(i + 3) * 256 + t256];
            }
            if (i + 1 < CL) wg_barrier();
        }
    } else {
#pragma unroll
        for (int i = 0; i < CL; ++i) {
            const float2 du = du_s[lb + i * ISTR2 + cg];
            const float dtp = du.x;
            const float uu = du.y;
            const float dtu = dtp * uu;
            const int l = cg * CL + i;
            const int k0 = 2 * h;
            float bv[8], cv[8];
#pragma unroll
            for (int q = 0; q < 8; ++q) {
                bv[q] = B_g[(size_t)(b * N + 4 * k0 + q) * L + l];
                cv[q] = C_g[(size_t)(b * N + 4 * k0 + q) * L + l];
            }
            float acc = 0.f;
#pragma unroll
            for (int n = 0; n < 8; ++n) {
                const float a = EXP2(dtp * A2[n]);
                const float xs = (n & 1) ? x2[n >> 1].y : x2[n >> 1].x;
                const float xn = fmaf(a, xs, dtu * bv[n]);
                if (n & 1) x2[n >> 1].y = xn; else x2[n >> 1].x = xn;
                acc = fmaf(xn, cv[n], acc);
            }
            acc += __shfl_xor(acc, 32, 64);
            const float yv = fmaf(uu, Dd, acc);
            y[i & 7] = ((i >> 3) == h) ? yv : y[i & 7];
        }
    }

    // ---- Epilogue: per-lane z read (32B), silu gate, y store from regs ----
    {
        const size_t gz = (size_t)row * L + cg * CL + h * 8;
        const float4 z0 = *reinterpret_cast<const float4*>(&z_g[gz]);
        const float4 z1 = *reinterpret_cast<const float4*>(&z_g[gz + 4]);
        float out[8];
#pragma unroll
        for (int j = 0; j < 8; ++j) {
            const float zv = (j < 4) ? (&z0.x)[j] : (&z1.x)[j - 4];
            const float e = EXP2(-zv * LOG2E);
            const float sig = __builtin_amdgcn_rcpf(1.f + e);
            out[j] = y[j] * (zv * sig);
        }
        *reinterpret_cast<float4*>(&y_g[gz]) =
            make_float4(out[0], out[1], out[2], out[3]);
        *reinterpret_cast<float4*>(&y_g[gz + 4]) =
            make_float4(out[4], out[5], out[6], out[7]);
    }
}

extern "C" void kernel_launch(void* const* d_in, const int* in_sizes, int n_in,
                              void* d_out, int out_size, void* d_ws, size_t ws_size,
                              hipStream_t stream) {
    const float* u     = (const float*)d_in[0];
    const float* delta = (const float*)d_in[1];
    const float* A     = (const float*)d_in[2];
    const float* B     = (const float*)d_in[3];
    const float* C     = (const float*)d_in[4];
    const float* D     = (const float*)d_in[5];
    const float* z     = (const float*)d_in[6];
    const float* bias  = (const float*)d_in[7];
    const int*   sp    = (const int*)d_in[8];
    float* y = (float*)d_out;

    const size_t bc_bytes = (size_t)Bsz * 4096 * sizeof(float4);  // 128 KB each
    const bool xf = ws_size >= 2 * bc_bytes;
    float4* Bs = (float4*)d_ws;
    float4* Cs = (float4*)((char*)d_ws + bc_bytes);

    if (xf) {
        transform_bc_kernel<<<dim3(16, Bsz, 2), 256, 0, stream>>>(B, C, Bs, Cs);
        mamba_scan27_kernel<true><<<dim3((Bsz * Dm) / RPB), TPB, 0, stream>>>(
            u, delta, A, B, C, Bs, Cs, D, z, bias, sp, y);
    } else {
        mamba_scan27_kernel<false><<<dim3((Bsz * Dm) / RPB), TPB, 0, stream>>>(
            u, delta, A, B, C, Bs, Cs, D, z, bias, sp, y);
    }
}